// Round 2
// baseline (2878.565 us; speedup 1.0000x reference)
//
#include <hip/hip_runtime.h>
#include <stdint.h>

#define B_ 8
#define L_ 2048
#define D_ 1024
#define Z_ 128
#define H_ 2048
#define NE_ 16
#define G_ 32
#define MAXPOS_ 2048
#define NMX_ 4224  // D + Z + H + D (u | z | r | hx)
#define EPS_ 1e-5f
#define PC_ 2.0f

typedef short bf16x8 __attribute__((ext_vector_type(8)));
typedef float f32x4 __attribute__((ext_vector_type(4)));

__device__ __forceinline__ float bf2f(uint16_t u) {
  union { uint32_t u; float f; } v; v.u = ((uint32_t)u) << 16; return v.f;
}
__device__ __forceinline__ uint16_t f2bf(float f) {
  union { float f; uint32_t u; } v; v.f = f;
  uint32_t r = (v.u + 0x7FFFu + ((v.u >> 16) & 1u)) >> 16;
  return (uint16_t)r;
}
__device__ __forceinline__ float sigmoidf_(float x) { return 1.f / (1.f + __expf(-x)); }
__device__ __forceinline__ float siluf_(float x) { return x / (1.f + __expf(-x)); }

__device__ __forceinline__ float waveRedSum(float v) {
  #pragma unroll
  for (int m = 32; m; m >>= 1) v += __shfl_xor(v, m, 64);
  return v;
}
__device__ __forceinline__ float waveRedMax(float v) {
  #pragma unroll
  for (int m = 32; m; m >>= 1) v = fmaxf(v, __shfl_xor(v, m, 64));
  return v;
}

// ---------------- fallback when workspace too small: encode ws MB in out[0] ----
__global__ __launch_bounds__(256) void k_fallback(float* __restrict__ out, int n, float wsmb) {
  for (int i = blockIdx.x * 256 + threadIdx.x; i < n; i += gridDim.x * 256)
    out[i] = (i == 0) ? wsmb : 0.f;
}

// ---------------- fp32 -> bf16 conversion (weights) ----------------
__global__ __launch_bounds__(256) void k_f2bf(const float* __restrict__ src,
                                              uint16_t* __restrict__ dst, int n) {
  for (int i = blockIdx.x * 256 + threadIdx.x; i < n; i += gridDim.x * 256)
    dst[i] = f2bf(src[i]);
}

// ---------------- TimestepNorm: causal cumulative group norm ----------------
__global__ __launch_bounds__(256) void k_tnorm(const float* __restrict__ x,
                                               const float* __restrict__ pm,
                                               const float* __restrict__ plv,
                                               const float* __restrict__ w,
                                               const float* __restrict__ bias,
                                               uint16_t* __restrict__ xn) {
  __shared__ float s1[L_];
  __shared__ float s2[L_];
  const int b = blockIdx.x / G_;
  const int g = blockIdx.x % G_;
  const int tid = threadIdx.x;
  const int j = tid & 31;
  const int lsub = tid >> 5;

  for (int basei = 0; basei < L_; basei += 8) {
    const int l = basei + lsub;
    float v = x[((size_t)(b * L_ + l)) * D_ + g * 32 + j];
    float a = v, sq = v * v;
    #pragma unroll
    for (int m = 1; m <= 16; m <<= 1) { a += __shfl_xor(a, m, 64); sq += __shfl_xor(sq, m, 64); }
    if (j == 0) { s1[l] = a; s2[l] = sq; }
  }
  __syncthreads();

  if (tid < 64) {
    const int lane = tid;
    #pragma unroll
    for (int pass = 0; pass < 2; ++pass) {
      float* s = pass ? s2 : s1;
      const int b0 = lane * 32;
      float tot = 0.f;
      for (int t = 0; t < 32; ++t) tot += s[b0 + t];
      float incl = tot;
      #pragma unroll
      for (int off = 1; off < 64; off <<= 1) {
        float nv = __shfl_up(incl, off, 64);
        if (lane >= off) incl += nv;
      }
      float run = incl - tot;
      for (int t = 0; t < 32; ++t) { run += s[b0 + t]; s[b0 + t] = run; }
    }
  }
  __syncthreads();

  const float pmv = pm[g];
  const float pvv = __expf(plv[g]);
  const float wj = w[g * 32 + j];
  const float bj = bias[g * 32 + j];
  const float pterm = PC_ * (pvv + pmv * pmv);
  for (int basei = 0; basei < L_; basei += 8) {
    const int l = basei + lsub;
    const size_t idx = ((size_t)(b * L_ + l)) * D_ + g * 32 + j;
    float v = x[idx];
    float cnt = PC_ + 32.f * (float)(l + 1);
    float mean = (PC_ * pmv + s1[l]) / cnt;
    float var = (pterm + s2[l]) / cnt - mean * mean;
    float o = (v - mean) * rsqrtf(var + EPS_) * wj + bj;
    xn[idx] = f2bf(o);
  }
}

// ---------------- generic 32x32-tiled transpose, batched over z ----------------
template <typename T>
__global__ __launch_bounds__(256) void k_transpose(const T* __restrict__ src,
                                                   T* __restrict__ dst, int R, int C) {
  __shared__ T tile[32][33];
  const size_t batch = (size_t)R * C * blockIdx.z;
  const int c0 = blockIdx.x * 32, r0 = blockIdx.y * 32;
  const int tx = threadIdx.x & 31, ty = threadIdx.x >> 5;
  #pragma unroll
  for (int k = 0; k < 4; ++k) {
    int r = ty + k * 8;
    tile[r][tx] = src[batch + (size_t)(r0 + r) * C + c0 + tx];
  }
  __syncthreads();
  #pragma unroll
  for (int k = 0; k < 4; ++k) {
    int r = ty + k * 8;
    dst[batch + (size_t)(c0 + r) * R + r0 + tx] = tile[tx][r];
  }
}

// ---------------- MultiHeadEMA via chunked linear recurrence ----------------
__global__ __launch_bounds__(64) void k_ema(const uint16_t* __restrict__ xnT,
                                            const float* __restrict__ delta,
                                            const float* __restrict__ alpha,
                                            const float* __restrict__ beta,
                                            const float* __restrict__ gamma,
                                            const float* __restrict__ omega,
                                            float* __restrict__ mxT) {
  __shared__ float hst[64 * NE_];
  const int bd = blockIdx.x;
  const int d = bd & (D_ - 1);
  const int c = threadIdx.x;

  float q[NE_], pb[NE_], gs[NE_];
  #pragma unroll
  for (int n = 0; n < NE_; ++n) {
    float p = sigmoidf_(delta[d * NE_ + n]);
    float a = sigmoidf_(alpha[d * NE_ + n]);
    q[n] = 1.f - p * a;
    pb[n] = p * beta[d * NE_ + n];
    gs[n] = gamma[d * NE_ + n] * 0.25f;
  }

  const uint16_t* xp = xnT + (size_t)bd * L_ + c * 32;
  float h[NE_];
  #pragma unroll
  for (int n = 0; n < NE_; ++n) h[n] = 0.f;

  for (int k = 0; k < 32; ++k) {
    float xv = bf2f(xp[k]);
    #pragma unroll
    for (int n = 0; n < NE_; ++n) h[n] = fmaf(q[n], h[n], pb[n] * xv);
  }
  #pragma unroll
  for (int n = 0; n < NE_; ++n) hst[c * NE_ + n] = h[n];
  __syncthreads();

  if (c < NE_) {
    float p = sigmoidf_(delta[d * NE_ + c]);
    float a = sigmoidf_(alpha[d * NE_ + c]);
    float qq = 1.f - p * a;
    float q32 = qq * qq; q32 *= q32; q32 *= q32; q32 *= q32; q32 *= q32;
    float hi = 0.f;
    for (int cc = 0; cc < 64; ++cc) {
      float cur = hst[cc * NE_ + c];
      hst[cc * NE_ + c] = hi;
      hi = fmaf(q32, hi, cur);
    }
  }
  __syncthreads();

  #pragma unroll
  for (int n = 0; n < NE_; ++n) h[n] = hst[c * NE_ + n];
  const float om = omega[d];
  float* op = mxT + (size_t)bd * L_ + c * 32;
  for (int k = 0; k < 32; ++k) {
    float xv = bf2f(xp[k]);
    float accv = 0.f;
    #pragma unroll
    for (int n = 0; n < NE_; ++n) {
      h[n] = fmaf(q[n], h[n], pb[n] * xv);
      accv = fmaf(gs[n], h[n], accv);
    }
    op[k] = accv + om * xv;
  }
}

// ---------------- RMS norm over D ----------------
__global__ __launch_bounds__(256) void k_rms(const float* __restrict__ mx,
                                             const float* __restrict__ w,
                                             uint16_t* __restrict__ mxn) {
  __shared__ float red[4];
  const size_t row = blockIdx.x;
  const int tid = threadIdx.x;
  float ss = 0.f;
  #pragma unroll
  for (int i = 0; i < 4; ++i) {
    float v = mx[row * D_ + tid + i * 256];
    ss += v * v;
  }
  ss = waveRedSum(ss);
  if ((tid & 63) == 0) red[tid >> 6] = ss;
  __syncthreads();
  ss = red[0] + red[1] + red[2] + red[3];
  const float scale = rsqrtf(ss * (1.f / D_) + EPS_);
  #pragma unroll
  for (int i = 0; i < 4; ++i) {
    int dcol = tid + i * 256;
    mxn[row * D_ + dcol] = f2bf(mx[row * D_ + dcol] * scale * w[dcol]);
  }
}

// ---------------- q/k prep from z ----------------
__global__ __launch_bounds__(256) void k_qkprep(const float* __restrict__ z,
                                                const float* __restrict__ qg,
                                                const float* __restrict__ qb,
                                                uint16_t* __restrict__ q,
                                                uint16_t* __restrict__ k, int n) {
  for (int i = blockIdx.x * 256 + threadIdx.x; i < n; i += gridDim.x * 256) {
    int zc = i & (Z_ - 1);
    float v = z[i];
    q[i] = f2bf((v * qg[zc] + qb[zc]) * 0.08838834764831845f);
    k[i] = f2bf(v * qg[Z_ + zc] + qb[Z_ + zc]);
  }
}

// ---------------- row softmax (causal), f32 in -> bf16 out ----------------
__global__ __launch_bounds__(256) void k_softmax(const float* __restrict__ scores,
                                                 uint16_t* __restrict__ pbuf) {
  __shared__ float buf[L_];
  __shared__ float red[4];
  const int i = blockIdx.x;
  const int n = i + 1;
  const int tid = threadIdx.x;
  const float* srow = scores + (size_t)i * L_;
  uint16_t* prow = pbuf + (size_t)i * L_;

  float mx = -3.4e38f;
  for (int j = tid; j < n; j += 256) { float v = srow[j]; buf[j] = v; mx = fmaxf(mx, v); }
  mx = waveRedMax(mx);
  if ((tid & 63) == 0) red[tid >> 6] = mx;
  __syncthreads();
  mx = fmaxf(fmaxf(red[0], red[1]), fmaxf(red[2], red[3]));
  __syncthreads();

  float s = 0.f;
  for (int j = tid; j < n; j += 256) { float e = __expf(buf[j] - mx); buf[j] = e; s += e; }
  s = waveRedSum(s);
  if ((tid & 63) == 0) red[tid >> 6] = s;
  __syncthreads();
  s = red[0] + red[1] + red[2] + red[3];
  const float inv = 1.f / s;
  for (int j = tid; j < L_; j += 256)
    prow[j] = (j < n) ? f2bf(buf[j] * inv) : (uint16_t)0;
}

// ---------------- MFMA GEMM: C = A(MxK,bf16) @ B(NxK,bf16)^T, fused epilogues ----
// MODE 0: V     out = silu(acc + bv[col])               -> bf16 v
// MODE 1: BASE  acc + bmx[col], split u(bf16)/z(f32)/r(bf16)/hx(f32)
// MODE 2: QK    acc + rel_bias[2047+col-row]            -> f32 scores (causal skip)
// MODE 3: PV    acc * r                                  -> bf16 hr (causal K-limit)
// MODE 4: WH    g=silu(acc+hx); out = x + u*(g-x)        -> f32 d_out
template <int MODE>
__global__ __launch_bounds__(256) void k_gemm(
    const uint16_t* __restrict__ A, const uint16_t* __restrict__ Bm,
    int M, int N, int K,
    const float* __restrict__ bias,
    float* __restrict__ outf, uint16_t* __restrict__ outb,
    uint16_t* __restrict__ ubuf, float* __restrict__ zbuf,
    uint16_t* __restrict__ rbuf, float* __restrict__ hxbuf,
    const float* __restrict__ relb, const uint16_t* __restrict__ rmul,
    const float* __restrict__ x0) {
  const int bm = blockIdx.x * 64;
  const int bn = blockIdx.y * 128;
  if (MODE == 2 && bn > bm + 63) return;  // fully-masked causal block
  const int tid = threadIdx.x;
  const int wave = tid >> 6, lane = tid & 63;
  const int quad = lane >> 4, r16 = lane & 15;
  const int wm = wave >> 1, wn = wave & 1;
  const int rowBase = bm + wm * 32;
  const int colBase = bn + wn * 64;
  const int kEnd = (MODE == 3) ? (K < bm + 64 ? K : bm + 64) : K;

  f32x4 acc[2][4];
  const f32x4 zf = {0.f, 0.f, 0.f, 0.f};
  #pragma unroll
  for (int i = 0; i < 2; ++i)
    #pragma unroll
    for (int j = 0; j < 4; ++j) acc[i][j] = zf;

  const uint16_t* ap = A + (size_t)(rowBase + r16) * K + quad * 8;
  const uint16_t* bp = Bm + (size_t)(colBase + r16) * K + quad * 8;
  const size_t rstep = (size_t)16 * K;

  for (int kb = 0; kb < kEnd; kb += 32) {
    bf16x8 a0 = *(const bf16x8*)(ap + kb);
    bf16x8 a1 = *(const bf16x8*)(ap + rstep + kb);
    bf16x8 b0 = *(const bf16x8*)(bp + kb);
    bf16x8 b1 = *(const bf16x8*)(bp + rstep + kb);
    bf16x8 b2 = *(const bf16x8*)(bp + 2 * rstep + kb);
    bf16x8 b3 = *(const bf16x8*)(bp + 3 * rstep + kb);
    acc[0][0] = __builtin_amdgcn_mfma_f32_16x16x32_bf16(a0, b0, acc[0][0], 0, 0, 0);
    acc[0][1] = __builtin_amdgcn_mfma_f32_16x16x32_bf16(a0, b1, acc[0][1], 0, 0, 0);
    acc[0][2] = __builtin_amdgcn_mfma_f32_16x16x32_bf16(a0, b2, acc[0][2], 0, 0, 0);
    acc[0][3] = __builtin_amdgcn_mfma_f32_16x16x32_bf16(a0, b3, acc[0][3], 0, 0, 0);
    acc[1][0] = __builtin_amdgcn_mfma_f32_16x16x32_bf16(a1, b0, acc[1][0], 0, 0, 0);
    acc[1][1] = __builtin_amdgcn_mfma_f32_16x16x32_bf16(a1, b1, acc[1][1], 0, 0, 0);
    acc[1][2] = __builtin_amdgcn_mfma_f32_16x16x32_bf16(a1, b2, acc[1][2], 0, 0, 0);
    acc[1][3] = __builtin_amdgcn_mfma_f32_16x16x32_bf16(a1, b3, acc[1][3], 0, 0, 0);
  }

  #pragma unroll
  for (int i = 0; i < 2; ++i) {
    #pragma unroll
    for (int j = 0; j < 4; ++j) {
      #pragma unroll
      for (int r = 0; r < 4; ++r) {
        const int row = rowBase + i * 16 + quad * 4 + r;
        const int col = colBase + j * 16 + r16;
        float val = acc[i][j][r];
        if (MODE == 0) {
          outb[(size_t)row * N + col] = f2bf(siluf_(val + bias[col]));
        } else if (MODE == 1) {
          val += bias[col];
          if (col < D_)                 ubuf[(size_t)row * D_ + col] = f2bf(sigmoidf_(val));
          else if (col < D_ + Z_)       zbuf[(size_t)row * Z_ + (col - D_)] = siluf_(val);
          else if (col < D_ + Z_ + H_)  rbuf[(size_t)row * H_ + (col - D_ - Z_)] = f2bf(siluf_(val));
          else                          hxbuf[(size_t)row * D_ + (col - D_ - Z_ - H_)] = val;
        } else if (MODE == 2) {
          val += relb[MAXPOS_ - 1 + col - row];
          outf[(size_t)row * N + col] = val;
        } else if (MODE == 3) {
          const size_t idx = (size_t)row * N + col;
          outb[idx] = f2bf(val * bf2f(rmul[idx]));
        } else {
          const size_t idx = (size_t)row * N + col;
          float g = siluf_(val + hxbuf[idx]);   // read hx (d_out) ...
          float xv = x0[idx];
          outf[idx] = xv + bf2f(ubuf[idx]) * (g - xv);  // ... then write out (same addr, same thread)
        }
      }
    }
  }
}

extern "C" void kernel_launch(void* const* d_in, const int* in_sizes, int n_in,
                              void* d_out, int out_size, void* d_ws, size_t ws_size,
                              hipStream_t stream) {
  (void)in_sizes; (void)n_in;
  const float* x         = (const float*)d_in[0];
  const float* prior_mean= (const float*)d_in[1];
  const float* prior_logv= (const float*)d_in[2];
  const float* tn_w      = (const float*)d_in[3];
  const float* tn_b      = (const float*)d_in[4];
  const float* delta     = (const float*)d_in[5];
  const float* alpha     = (const float*)d_in[6];
  const float* ema_beta  = (const float*)d_in[7];
  const float* ema_gamma = (const float*)d_in[8];
  const float* omega     = (const float*)d_in[9];
  const float* rms_w     = (const float*)d_in[10];
  const float* Wv        = (const float*)d_in[11];
  const float* bv        = (const float*)d_in[12];
  const float* Wmx       = (const float*)d_in[13];
  const float* bmx       = (const float*)d_in[14];
  const float* Wh        = (const float*)d_in[15];
  const float* qk_gamma  = (const float*)d_in[16];
  const float* qk_beta   = (const float*)d_in[17];
  const float* rel_bias  = (const float*)d_in[18];
  float* out = (float*)d_out;

  const int BL = B_ * L_;
  const size_t MB = 1024 * 1024;
  const size_t REQUIRED = 256 * MB;   // exact: 2x32MB + 3x64MB regions

  if (ws_size < REQUIRED) {
    // cannot run safely; write zeros and encode ws_size (in MB) into out[0]
    k_fallback<<<dim3(4096), dim3(256), 0, stream>>>(out, out_size, (float)(ws_size / MB));
    return;
  }

  char* p = (char*)d_ws;
  // RA [0,32MB): xn -> mxn -> {q | k | scores | pbuf}
  uint16_t* xn     = (uint16_t*)(p);
  uint16_t* mxn    = (uint16_t*)(p);
  uint16_t* qb     = (uint16_t*)(p);
  uint16_t* kb2    = (uint16_t*)(p + 4 * MB);
  float*    scores = (float*)   (p + 8 * MB);
  uint16_t* pbuf   = (uint16_t*)(p + 24 * MB);
  // RB [32MB,64MB): xnT -> u(bf16)
  uint16_t* xnT  = (uint16_t*)(p + 32 * MB);
  uint16_t* ubuf = (uint16_t*)(p + 32 * MB);
  // RC [64MB,128MB): v -> r -> Wh(bf16)
  uint16_t* vbuf = (uint16_t*)(p + 64 * MB);
  uint16_t* rbuf = (uint16_t*)(p + 64 * MB);
  uint16_t* wh_b = (uint16_t*)(p + 64 * MB);
  // RD [128MB,192MB): Wv(bf16) -> vT
  uint16_t* wv_b = (uint16_t*)(p + 128 * MB);
  uint16_t* vT   = (uint16_t*)(p + 128 * MB);
  // RE [192MB,256MB): mx(f32) -> {z(f32) | Wmx(bf16) @+16MB} -> hr
  float*    mx    = (float*)   (p + 192 * MB);
  float*    zb    = (float*)   (p + 192 * MB);
  uint16_t* wmx_b = (uint16_t*)(p + 208 * MB);
  uint16_t* hr    = (uint16_t*)(p + 192 * MB);
  // d_out doubles as: mxT (steps 6-7) -> hx f32 (steps 9-12) -> out
  float* mxT = out;
  float* hx  = out;

  // 1. Wv -> bf16 (into RD, dead until vT at step 5)
  k_f2bf<<<dim3(1024), dim3(256), 0, stream>>>(Wv, wv_b, H_ * D_);
  // 2. timestep norm -> xn (RA)
  k_tnorm<<<dim3(B_ * G_), dim3(256), 0, stream>>>(x, prior_mean, prior_logv, tn_w, tn_b, xn);
  // 3. xn -> xnT (RB)
  k_transpose<uint16_t><<<dim3(D_ / 32, L_ / 32, B_), dim3(256), 0, stream>>>(xn, xnT, L_, D_);
  // 4. v = silu(xn @ Wv^T + bv) -> vbuf (RC)
  k_gemm<0><<<dim3(BL / 64, H_ / 128), dim3(256), 0, stream>>>(
      xn, wv_b, BL, H_, D_, bv, nullptr, vbuf,
      nullptr, nullptr, nullptr, nullptr, nullptr, nullptr, nullptr);
  // 5. v -> vT (RD; overwrites dead wv_b)
  k_transpose<uint16_t><<<dim3(H_ / 32, L_ / 32, B_), dim3(256), 0, stream>>>(vbuf, vT, L_, H_);
  // 6. EMA: xnT -> mxT (d_out)
  k_ema<<<dim3(B_ * D_), dim3(64), 0, stream>>>(xnT, delta, alpha, ema_beta, ema_gamma, omega, mxT);
  // 7. mxT -> mx (RE)
  k_transpose<float><<<dim3(L_ / 32, D_ / 32, B_), dim3(256), 0, stream>>>(mxT, mx, D_, L_);
  // 8. RMS norm -> mxn (RA; xn dead)
  k_rms<<<dim3(BL), dim3(256), 0, stream>>>(mx, rms_w, mxn);
  // 9. Wmx -> bf16 (RE+16MB; mx dead after step 8)
  k_f2bf<<<dim3(2048), dim3(256), 0, stream>>>(Wmx, wmx_b, NMX_ * D_);
  // 10. base = mxn @ Wmx^T + bmx -> u(RB) z(RE) r(RC) hx(d_out)
  k_gemm<1><<<dim3(BL / 64, NMX_ / 128), dim3(256), 0, stream>>>(
      mxn, wmx_b, BL, NMX_, D_, bmx, nullptr, nullptr,
      ubuf, zb, rbuf, hx, nullptr, nullptr, nullptr);
  // 11. q,k from z (RA; mxn dead)
  k_qkprep<<<dim3(1024), dim3(256), 0, stream>>>(zb, qk_gamma, qk_beta, qb, kb2, BL * Z_);
  // 12. attention per batch: scores/pbuf in RA, hr in RE (z,wmx dead)
  for (int b = 0; b < B_; ++b) {
    k_gemm<2><<<dim3(L_ / 64, L_ / 128), dim3(256), 0, stream>>>(
        qb + (size_t)b * L_ * Z_, kb2 + (size_t)b * L_ * Z_, L_, L_, Z_,
        nullptr, scores, nullptr, nullptr, nullptr, nullptr, nullptr, rel_bias, nullptr, nullptr);
    k_softmax<<<dim3(L_), dim3(256), 0, stream>>>(scores, pbuf);
    k_gemm<3><<<dim3(L_ / 64, H_ / 128), dim3(256), 0, stream>>>(
        pbuf, vT + (size_t)b * H_ * L_, L_, H_, L_,
        nullptr, nullptr, hr + (size_t)b * L_ * H_, nullptr, nullptr, nullptr, nullptr,
        nullptr, rbuf + (size_t)b * L_ * H_, nullptr);
  }
  // 13. Wh -> bf16 (RC; rbuf dead after step 12)
  k_f2bf<<<dim3(1024), dim3(256), 0, stream>>>(Wh, wh_b, D_ * H_);
  // 14. final: g = silu(hx + hr@Wh^T); out = x + u*(g-x)
  k_gemm<4><<<dim3(BL / 64, D_ / 128), dim3(256), 0, stream>>>(
      hr, wh_b, BL, D_, H_, nullptr, out, nullptr,
      ubuf, nullptr, nullptr, hx, nullptr, nullptr, x);
}

// Round 3
// 1636.129 us; speedup vs baseline: 1.7594x; 1.7594x over previous
//
#include <hip/hip_runtime.h>
#include <stdint.h>

#define B_ 8
#define L_ 2048
#define D_ 1024
#define Z_ 128
#define H_ 2048
#define NE_ 16
#define G_ 32
#define MAXPOS_ 2048
#define NMX_ 4224  // D + Z + H + D (u | z | r | hx)
#define EPS_ 1e-5f
#define PC_ 2.0f

typedef short bf16x8 __attribute__((ext_vector_type(8)));
typedef float f32x4 __attribute__((ext_vector_type(4)));

__device__ __forceinline__ float bf2f(uint16_t u) {
  union { uint32_t u; float f; } v; v.u = ((uint32_t)u) << 16; return v.f;
}
__device__ __forceinline__ uint16_t f2bf(float f) {
  union { float f; uint32_t u; } v; v.f = f;
  uint32_t r = (v.u + 0x7FFFu + ((v.u >> 16) & 1u)) >> 16;
  return (uint16_t)r;
}
__device__ __forceinline__ float sigmoidf_(float x) { return 1.f / (1.f + __expf(-x)); }
__device__ __forceinline__ float siluf_(float x) { return x / (1.f + __expf(-x)); }

__device__ __forceinline__ float waveRedSum(float v) {
  #pragma unroll
  for (int m = 32; m; m >>= 1) v += __shfl_xor(v, m, 64);
  return v;
}
__device__ __forceinline__ float waveRedMax(float v) {
  #pragma unroll
  for (int m = 32; m; m >>= 1) v = fmaxf(v, __shfl_xor(v, m, 64));
  return v;
}

// async global->LDS, 16 bytes per lane; lds dst must be waveBase + lane*16
__device__ __forceinline__ void gl2lds(const uint16_t* g, uint16_t* l) {
  __builtin_amdgcn_global_load_lds(
      (const __attribute__((address_space(1))) void*)g,
      (__attribute__((address_space(3))) void*)l, 16, 0, 0);
}

// ---------------- fallback when workspace too small: encode ws MB in out[0] ----
__global__ __launch_bounds__(256) void k_fallback(float* __restrict__ out, int n, float wsmb) {
  for (int i = blockIdx.x * 256 + threadIdx.x; i < n; i += gridDim.x * 256)
    out[i] = (i == 0) ? wsmb : 0.f;
}

// ---------------- fp32 -> bf16 conversion (weights) ----------------
__global__ __launch_bounds__(256) void k_f2bf(const float* __restrict__ src,
                                              uint16_t* __restrict__ dst, int n) {
  for (int i = blockIdx.x * 256 + threadIdx.x; i < n; i += gridDim.x * 256)
    dst[i] = f2bf(src[i]);
}

// ---------------- TimestepNorm: causal cumulative group norm ----------------
__global__ __launch_bounds__(256) void k_tnorm(const float* __restrict__ x,
                                               const float* __restrict__ pm,
                                               const float* __restrict__ plv,
                                               const float* __restrict__ w,
                                               const float* __restrict__ bias,
                                               uint16_t* __restrict__ xn) {
  __shared__ float s1[L_];
  __shared__ float s2[L_];
  const int b = blockIdx.x / G_;
  const int g = blockIdx.x % G_;
  const int tid = threadIdx.x;
  const int j = tid & 31;
  const int lsub = tid >> 5;

  for (int basei = 0; basei < L_; basei += 8) {
    const int l = basei + lsub;
    float v = x[((size_t)(b * L_ + l)) * D_ + g * 32 + j];
    float a = v, sq = v * v;
    #pragma unroll
    for (int m = 1; m <= 16; m <<= 1) { a += __shfl_xor(a, m, 64); sq += __shfl_xor(sq, m, 64); }
    if (j == 0) { s1[l] = a; s2[l] = sq; }
  }
  __syncthreads();

  if (tid < 64) {
    const int lane = tid;
    #pragma unroll
    for (int pass = 0; pass < 2; ++pass) {
      float* s = pass ? s2 : s1;
      const int b0 = lane * 32;
      float tot = 0.f;
      for (int t = 0; t < 32; ++t) tot += s[b0 + t];
      float incl = tot;
      #pragma unroll
      for (int off = 1; off < 64; off <<= 1) {
        float nv = __shfl_up(incl, off, 64);
        if (lane >= off) incl += nv;
      }
      float run = incl - tot;
      for (int t = 0; t < 32; ++t) { run += s[b0 + t]; s[b0 + t] = run; }
    }
  }
  __syncthreads();

  const float pmv = pm[g];
  const float pvv = __expf(plv[g]);
  const float wj = w[g * 32 + j];
  const float bj = bias[g * 32 + j];
  const float pterm = PC_ * (pvv + pmv * pmv);
  for (int basei = 0; basei < L_; basei += 8) {
    const int l = basei + lsub;
    const size_t idx = ((size_t)(b * L_ + l)) * D_ + g * 32 + j;
    float v = x[idx];
    float cnt = PC_ + 32.f * (float)(l + 1);
    float mean = (PC_ * pmv + s1[l]) / cnt;
    float var = (pterm + s2[l]) / cnt - mean * mean;
    float o = (v - mean) * rsqrtf(var + EPS_) * wj + bj;
    xn[idx] = f2bf(o);
  }
}

// ---------------- generic 32x32-tiled transpose, batched over z ----------------
template <typename T>
__global__ __launch_bounds__(256) void k_transpose(const T* __restrict__ src,
                                                   T* __restrict__ dst, int R, int C) {
  __shared__ T tile[32][33];
  const size_t batch = (size_t)R * C * blockIdx.z;
  const int c0 = blockIdx.x * 32, r0 = blockIdx.y * 32;
  const int tx = threadIdx.x & 31, ty = threadIdx.x >> 5;
  #pragma unroll
  for (int k = 0; k < 4; ++k) {
    int r = ty + k * 8;
    tile[r][tx] = src[batch + (size_t)(r0 + r) * C + c0 + tx];
  }
  __syncthreads();
  #pragma unroll
  for (int k = 0; k < 4; ++k) {
    int r = ty + k * 8;
    dst[batch + (size_t)(c0 + r) * R + r0 + tx] = tile[tx][r];
  }
}

// ---------------- MultiHeadEMA via chunked linear recurrence ----------------
__global__ __launch_bounds__(64) void k_ema(const uint16_t* __restrict__ xnT,
                                            const float* __restrict__ delta,
                                            const float* __restrict__ alpha,
                                            const float* __restrict__ beta,
                                            const float* __restrict__ gamma,
                                            const float* __restrict__ omega,
                                            float* __restrict__ mxT) {
  __shared__ float hst[64 * NE_];
  const int bd = blockIdx.x;
  const int d = bd & (D_ - 1);
  const int c = threadIdx.x;

  float q[NE_], pb[NE_], gs[NE_];
  #pragma unroll
  for (int n = 0; n < NE_; ++n) {
    float p = sigmoidf_(delta[d * NE_ + n]);
    float a = sigmoidf_(alpha[d * NE_ + n]);
    q[n] = 1.f - p * a;
    pb[n] = p * beta[d * NE_ + n];
    gs[n] = gamma[d * NE_ + n] * 0.25f;
  }

  const uint16_t* xp = xnT + (size_t)bd * L_ + c * 32;
  float h[NE_];
  #pragma unroll
  for (int n = 0; n < NE_; ++n) h[n] = 0.f;

  for (int k = 0; k < 32; ++k) {
    float xv = bf2f(xp[k]);
    #pragma unroll
    for (int n = 0; n < NE_; ++n) h[n] = fmaf(q[n], h[n], pb[n] * xv);
  }
  #pragma unroll
  for (int n = 0; n < NE_; ++n) hst[c * NE_ + n] = h[n];
  __syncthreads();

  if (c < NE_) {
    float p = sigmoidf_(delta[d * NE_ + c]);
    float a = sigmoidf_(alpha[d * NE_ + c]);
    float qq = 1.f - p * a;
    float q32 = qq * qq; q32 *= q32; q32 *= q32; q32 *= q32; q32 *= q32;
    float hi = 0.f;
    for (int cc = 0; cc < 64; ++cc) {
      float cur = hst[cc * NE_ + c];
      hst[cc * NE_ + c] = hi;
      hi = fmaf(q32, hi, cur);
    }
  }
  __syncthreads();

  #pragma unroll
  for (int n = 0; n < NE_; ++n) h[n] = hst[c * NE_ + n];
  const float om = omega[d];
  float* op = mxT + (size_t)bd * L_ + c * 32;
  for (int k = 0; k < 32; ++k) {
    float xv = bf2f(xp[k]);
    float accv = 0.f;
    #pragma unroll
    for (int n = 0; n < NE_; ++n) {
      h[n] = fmaf(q[n], h[n], pb[n] * xv);
      accv = fmaf(gs[n], h[n], accv);
    }
    op[k] = accv + om * xv;
  }
}

// ---------------- RMS norm over D ----------------
__global__ __launch_bounds__(256) void k_rms(const float* __restrict__ mx,
                                             const float* __restrict__ w,
                                             uint16_t* __restrict__ mxn) {
  __shared__ float red[4];
  const size_t row = blockIdx.x;
  const int tid = threadIdx.x;
  float ss = 0.f;
  #pragma unroll
  for (int i = 0; i < 4; ++i) {
    float v = mx[row * D_ + tid + i * 256];
    ss += v * v;
  }
  ss = waveRedSum(ss);
  if ((tid & 63) == 0) red[tid >> 6] = ss;
  __syncthreads();
  ss = red[0] + red[1] + red[2] + red[3];
  const float scale = rsqrtf(ss * (1.f / D_) + EPS_);
  #pragma unroll
  for (int i = 0; i < 4; ++i) {
    int dcol = tid + i * 256;
    mxn[row * D_ + dcol] = f2bf(mx[row * D_ + dcol] * scale * w[dcol]);
  }
}

// ---------------- q/k prep from z ----------------
__global__ __launch_bounds__(256) void k_qkprep(const float* __restrict__ z,
                                                const float* __restrict__ qg,
                                                const float* __restrict__ qb,
                                                uint16_t* __restrict__ q,
                                                uint16_t* __restrict__ k, int n) {
  for (int i = blockIdx.x * 256 + threadIdx.x; i < n; i += gridDim.x * 256) {
    int zc = i & (Z_ - 1);
    float v = z[i];
    q[i] = f2bf((v * qg[zc] + qb[zc]) * 0.08838834764831845f);
    k[i] = f2bf(v * qg[Z_ + zc] + qb[Z_ + zc]);
  }
}

// ---------------- row softmax (causal), f32 in -> bf16 out ----------------
__global__ __launch_bounds__(256) void k_softmax(const float* __restrict__ scores,
                                                 uint16_t* __restrict__ pbuf) {
  __shared__ float buf[L_];
  __shared__ float red[4];
  const int i = blockIdx.x;
  const int n = i + 1;
  const int tid = threadIdx.x;
  const float* srow = scores + (size_t)i * L_;
  uint16_t* prow = pbuf + (size_t)i * L_;

  float mx = -3.4e38f;
  for (int j = tid; j < n; j += 256) { float v = srow[j]; buf[j] = v; mx = fmaxf(mx, v); }
  mx = waveRedMax(mx);
  if ((tid & 63) == 0) red[tid >> 6] = mx;
  __syncthreads();
  mx = fmaxf(fmaxf(red[0], red[1]), fmaxf(red[2], red[3]));
  __syncthreads();

  float s = 0.f;
  for (int j = tid; j < n; j += 256) { float e = __expf(buf[j] - mx); buf[j] = e; s += e; }
  s = waveRedSum(s);
  if ((tid & 63) == 0) red[tid >> 6] = s;
  __syncthreads();
  s = red[0] + red[1] + red[2] + red[3];
  const float inv = 1.f / s;
  for (int j = tid; j < L_; j += 256)
    prow[j] = (j < n) ? f2bf(buf[j] * inv) : (uint16_t)0;
}

// ---- MFMA GEMM, m97 structure: 128x128 tile, BK=32, global_load_lds staging ----
// C = A(MxK,bf16) @ B(NxK,bf16)^T with fused epilogues:
// MODE 0: V     out = silu(acc + bv[col])               -> bf16 v
// MODE 1: BASE  acc + bmx[col], split u(bf16)/z(f32)/r(bf16)/hx(f32)
// MODE 2: QK    acc + rel_bias[2047+col-row]            -> f32 scores (causal block skip)
// MODE 3: PV    acc * r                                  -> bf16 hr (causal K-limit bm+128)
// MODE 4: WH    g=silu(acc+hx); out = x + u*(g-x)        -> f32 d_out
template <int MODE>
__global__ __launch_bounds__(256) void k_gemm(
    const uint16_t* __restrict__ A, const uint16_t* __restrict__ Bm,
    int N, int K,
    const float* __restrict__ bias,
    float* __restrict__ outf, uint16_t* __restrict__ outb,
    uint16_t* __restrict__ ubuf, float* __restrict__ zbuf,
    uint16_t* __restrict__ rbuf, float* __restrict__ hxbuf,
    const float* __restrict__ relb, const uint16_t* __restrict__ rmul,
    const float* __restrict__ x0) {
  const int bm = blockIdx.x * 128;
  const int bn = blockIdx.y * 128;
  if (MODE == 2 && bn >= bm + 128) return;  // fully-masked causal block
  __shared__ uint16_t As[128 * 32];
  __shared__ uint16_t Bs[128 * 32];
  const int tid = threadIdx.x;
  const int wave = tid >> 6, lane = tid & 63;
  const int quad = lane >> 4, r16 = lane & 15;
  const int wm = wave >> 1, wn = wave & 1;
  const int rowW = wm * 64, colW = wn * 64;
  const int kEnd = (MODE == 3) ? (K < bm + 128 ? K : bm + 128) : K;

  f32x4 acc[4][4];
  const f32x4 zf = {0.f, 0.f, 0.f, 0.f};
  #pragma unroll
  for (int i = 0; i < 4; ++i)
    #pragma unroll
    for (int j = 0; j < 4; ++j) acc[i][j] = zf;

  // staging map: thread t -> row t/4 (and +64), 8-elem segment (t%4)*8
  const int rA = tid >> 2;
  const int sg = (tid & 3) * 8;
  const uint16_t* gA0 = A + (size_t)(bm + rA) * K + sg;
  const uint16_t* gA1 = A + (size_t)(bm + 64 + rA) * K + sg;
  const uint16_t* gB0 = Bm + (size_t)(bn + rA) * K + sg;
  const uint16_t* gB1 = Bm + (size_t)(bn + 64 + rA) * K + sg;
  uint16_t* lA0 = As + tid * 8;          // byte offset tid*16: wave base + lane*16
  uint16_t* lA1 = As + 2048 + tid * 8;
  uint16_t* lB0 = Bs + tid * 8;
  uint16_t* lB1 = Bs + 2048 + tid * 8;

  for (int kb = 0; kb < kEnd; kb += 32) {
    __syncthreads();
    gl2lds(gA0 + kb, lA0);
    gl2lds(gA1 + kb, lA1);
    gl2lds(gB0 + kb, lB0);
    gl2lds(gB1 + kb, lB1);
    __syncthreads();  // compiler emits vmcnt(0) drain before barrier
    bf16x8 af[4], bfr[4];
    #pragma unroll
    for (int i = 0; i < 4; ++i)
      af[i] = *(const bf16x8*)&As[(rowW + i * 16 + r16) * 32 + quad * 8];
    #pragma unroll
    for (int j = 0; j < 4; ++j)
      bfr[j] = *(const bf16x8*)&Bs[(colW + j * 16 + r16) * 32 + quad * 8];
    #pragma unroll
    for (int i = 0; i < 4; ++i)
      #pragma unroll
      for (int j = 0; j < 4; ++j)
        acc[i][j] = __builtin_amdgcn_mfma_f32_16x16x32_bf16(af[i], bfr[j], acc[i][j], 0, 0, 0);
  }

  #pragma unroll
  for (int i = 0; i < 4; ++i) {
    #pragma unroll
    for (int j = 0; j < 4; ++j) {
      #pragma unroll
      for (int r = 0; r < 4; ++r) {
        const int row = bm + rowW + i * 16 + quad * 4 + r;
        const int col = bn + colW + j * 16 + r16;
        float val = acc[i][j][r];
        if (MODE == 0) {
          outb[(size_t)row * N + col] = f2bf(siluf_(val + bias[col]));
        } else if (MODE == 1) {
          val += bias[col];
          if (col < D_)                 ubuf[(size_t)row * D_ + col] = f2bf(sigmoidf_(val));
          else if (col < D_ + Z_)       zbuf[(size_t)row * Z_ + (col - D_)] = siluf_(val);
          else if (col < D_ + Z_ + H_)  rbuf[(size_t)row * H_ + (col - D_ - Z_)] = f2bf(siluf_(val));
          else                          hxbuf[(size_t)row * D_ + (col - D_ - Z_ - H_)] = val;
        } else if (MODE == 2) {
          val += relb[MAXPOS_ - 1 + col - row];
          outf[(size_t)row * N + col] = val;
        } else if (MODE == 3) {
          const size_t idx = (size_t)row * N + col;
          outb[idx] = f2bf(val * bf2f(rmul[idx]));
        } else {
          const size_t idx = (size_t)row * N + col;
          float g = siluf_(val + hxbuf[idx]);   // read hx (d_out) ...
          float xv = x0[idx];
          outf[idx] = xv + bf2f(ubuf[idx]) * (g - xv);  // ... then write same addr
        }
      }
    }
  }
}

extern "C" void kernel_launch(void* const* d_in, const int* in_sizes, int n_in,
                              void* d_out, int out_size, void* d_ws, size_t ws_size,
                              hipStream_t stream) {
  (void)in_sizes; (void)n_in;
  const float* x         = (const float*)d_in[0];
  const float* prior_mean= (const float*)d_in[1];
  const float* prior_logv= (const float*)d_in[2];
  const float* tn_w      = (const float*)d_in[3];
  const float* tn_b      = (const float*)d_in[4];
  const float* delta     = (const float*)d_in[5];
  const float* alpha     = (const float*)d_in[6];
  const float* ema_beta  = (const float*)d_in[7];
  const float* ema_gamma = (const float*)d_in[8];
  const float* omega     = (const float*)d_in[9];
  const float* rms_w     = (const float*)d_in[10];
  const float* Wv        = (const float*)d_in[11];
  const float* bv        = (const float*)d_in[12];
  const float* Wmx       = (const float*)d_in[13];
  const float* bmx       = (const float*)d_in[14];
  const float* Wh        = (const float*)d_in[15];
  const float* qk_gamma  = (const float*)d_in[16];
  const float* qk_beta   = (const float*)d_in[17];
  const float* rel_bias  = (const float*)d_in[18];
  float* out = (float*)d_out;

  const int BL = B_ * L_;
  const size_t MB = 1024 * 1024;
  const size_t REQUIRED = 256 * MB;

  if (ws_size < REQUIRED) {
    k_fallback<<<dim3(4096), dim3(256), 0, stream>>>(out, out_size, (float)(ws_size / MB));
    return;
  }

  char* p = (char*)d_ws;
  // RA [0,32MB): xn -> mxn -> {q | k | scores | pbuf}
  uint16_t* xn     = (uint16_t*)(p);
  uint16_t* mxn    = (uint16_t*)(p);
  uint16_t* qb     = (uint16_t*)(p);
  uint16_t* kb2    = (uint16_t*)(p + 4 * MB);
  float*    scores = (float*)   (p + 8 * MB);
  uint16_t* pbuf   = (uint16_t*)(p + 24 * MB);
  // RB [32MB,64MB): xnT -> u(bf16)
  uint16_t* xnT  = (uint16_t*)(p + 32 * MB);
  uint16_t* ubuf = (uint16_t*)(p + 32 * MB);
  // RC [64MB,128MB): v -> r -> Wh(bf16)
  uint16_t* vbuf = (uint16_t*)(p + 64 * MB);
  uint16_t* rbuf = (uint16_t*)(p + 64 * MB);
  uint16_t* wh_b = (uint16_t*)(p + 64 * MB);
  // RD [128MB,192MB): Wv(bf16) -> vT
  uint16_t* wv_b = (uint16_t*)(p + 128 * MB);
  uint16_t* vT   = (uint16_t*)(p + 128 * MB);
  // RE [192MB,256MB): mx(f32) -> {z(f32) | Wmx(bf16) @+16MB} -> hr
  float*    mx    = (float*)   (p + 192 * MB);
  float*    zb    = (float*)   (p + 192 * MB);
  uint16_t* wmx_b = (uint16_t*)(p + 208 * MB);
  uint16_t* hr    = (uint16_t*)(p + 192 * MB);
  // d_out doubles as: mxT (steps 6-7) -> hx f32 (steps 9-12) -> out
  float* mxT = out;
  float* hx  = out;

  // 1. Wv -> bf16 (RD, dead until vT at step 5)
  k_f2bf<<<dim3(1024), dim3(256), 0, stream>>>(Wv, wv_b, H_ * D_);
  // 2. timestep norm -> xn (RA)
  k_tnorm<<<dim3(B_ * G_), dim3(256), 0, stream>>>(x, prior_mean, prior_logv, tn_w, tn_b, xn);
  // 3. xn -> xnT (RB)
  k_transpose<uint16_t><<<dim3(D_ / 32, L_ / 32, B_), dim3(256), 0, stream>>>(xn, xnT, L_, D_);
  // 4. v = silu(xn @ Wv^T + bv) -> vbuf (RC)
  k_gemm<0><<<dim3(BL / 128, H_ / 128), dim3(256), 0, stream>>>(
      xn, wv_b, H_, D_, bv, nullptr, vbuf,
      nullptr, nullptr, nullptr, nullptr, nullptr, nullptr, nullptr);
  // 5. v -> vT (RD; overwrites dead wv_b)
  k_transpose<uint16_t><<<dim3(H_ / 32, L_ / 32, B_), dim3(256), 0, stream>>>(vbuf, vT, L_, H_);
  // 6. EMA: xnT -> mxT (d_out)
  k_ema<<<dim3(B_ * D_), dim3(64), 0, stream>>>(xnT, delta, alpha, ema_beta, ema_gamma, omega, mxT);
  // 7. mxT -> mx (RE)
  k_transpose<float><<<dim3(L_ / 32, D_ / 32, B_), dim3(256), 0, stream>>>(mxT, mx, D_, L_);
  // 8. RMS norm -> mxn (RA; xn dead)
  k_rms<<<dim3(BL), dim3(256), 0, stream>>>(mx, rms_w, mxn);
  // 9. Wmx -> bf16 (RE+16MB; mx dead)
  k_f2bf<<<dim3(2048), dim3(256), 0, stream>>>(Wmx, wmx_b, NMX_ * D_);
  // 10. base = mxn @ Wmx^T + bmx -> u(RB) z(RE) r(RC) hx(d_out)
  k_gemm<1><<<dim3(BL / 128, NMX_ / 128), dim3(256), 0, stream>>>(
      mxn, wmx_b, NMX_, D_, bmx, nullptr, nullptr,
      ubuf, zb, rbuf, hx, nullptr, nullptr, nullptr);
  // 11. q,k from z (RA; mxn dead)
  k_qkprep<<<dim3(1024), dim3(256), 0, stream>>>(zb, qk_gamma, qk_beta, qb, kb2, BL * Z_);
  // 12. attention per batch: scores/pbuf in RA, hr in RE
  for (int b = 0; b < B_; ++b) {
    k_gemm<2><<<dim3(L_ / 128, L_ / 128), dim3(256), 0, stream>>>(
        qb + (size_t)b * L_ * Z_, kb2 + (size_t)b * L_ * Z_, L_, Z_,
        nullptr, scores, nullptr, nullptr, nullptr, nullptr, nullptr, rel_bias, nullptr, nullptr);
    k_softmax<<<dim3(L_), dim3(256), 0, stream>>>(scores, pbuf);
    k_gemm<3><<<dim3(L_ / 128, H_ / 128), dim3(256), 0, stream>>>(
        pbuf, vT + (size_t)b * H_ * L_, H_, L_,
        nullptr, nullptr, hr + (size_t)b * L_ * H_, nullptr, nullptr, nullptr, nullptr,
        nullptr, rbuf + (size_t)b * L_ * H_, nullptr);
  }
  // 13. Wh -> bf16 (RC; rbuf dead after step 12)
  k_f2bf<<<dim3(1024), dim3(256), 0, stream>>>(Wh, wh_b, D_ * H_);
  // 14. final: g = silu(hx + hr@Wh^T); out = x + u*(g-x)
  k_gemm<4><<<dim3(BL / 128, D_ / 128), dim3(256), 0, stream>>>(
      hr, wh_b, D_, H_, nullptr, out, nullptr,
      ubuf, nullptr, nullptr, hx, nullptr, nullptr, x);
}